// Round 6
// baseline (135.830 us; speedup 1.0000x reference)
//
#include <hip/hip_runtime.h>
#include <hip/hip_bf16.h>

// PairwiseScore: B=2, N=256, E=512, H=150 (padded to 160)
// out[b,i,j] = (m[b,i] + m[b,j] + MLP3(g_i, g_j)) / 3
//
// Fold: hij + hj = sum_e (g_i[e]*W1c[e,h] + W1b[e,h]) * g_j[e]
// R6: split the monolith into two kernels so 2+ blocks/CU overlap stalls
// (R3-R5 all pinned at ~64us with 1 block/CU and barrier-serialized phases):
//  - pair_h1: grid 1024 = (b,i,hg), 512 thr. hg splits the h range (PARTITIONS
//    the builder, unlike R2's j-split which duplicated it). acc=40 AGPR,
//    ~47KB LDS -> 2 resident blocks/CU. Writes h1 (41.9MB bf16) to ws in
//    pre-swizzled B-frag layout via LDS transpose.
//  - pair_out: grid 1024 = (b,i,jh), K=160 GEMM; B-frags coalesced directly
//    from ws (no transform), W2 A-frags from L2 ping-pong. 1 barrier + combine.

typedef __attribute__((ext_vector_type(4))) float f32x4;
typedef __attribute__((ext_vector_type(4))) unsigned int u32x4;
typedef __attribute__((ext_vector_type(2))) unsigned int u32x2;
typedef __attribute__((ext_vector_type(8))) short short8;

#define NB 2
#define NN 256
#define NE 512
#define NH 150
#define HP 160      // padded H
#define NKT 16      // NE/32 k-tiles for GEMM1
#define NHT 10      // HP/16 h-tiles
#define NS 5        // HP/32 k-steps for GEMM2
#define TS 44       // transpose-buffer j-row stride in u32 (176B: 16B-aligned units)

// ---------- helpers ----------
__device__ __forceinline__ unsigned pk_bf16(float a, float b) {
  unsigned ua = __builtin_bit_cast(unsigned, a);
  unsigned ub = __builtin_bit_cast(unsigned, b);
  ua += 0x7fffu + ((ua >> 16) & 1u);
  ub += 0x7fffu + ((ub >> 16) & 1u);
  return (ua >> 16) | (ub & 0xffff0000u);
}
__device__ __forceinline__ float bf_lo(unsigned u) { return __builtin_bit_cast(float, u << 16); }
__device__ __forceinline__ float bf_hi(unsigned u) { return __builtin_bit_cast(float, u & 0xffff0000u); }

// ---------- prep: grid 466 x 256, one (row,q) per thread (unchanged R5) ----------
__global__ __launch_bounds__(256) void prep_pack(
    const float* __restrict__ g, const float* __restrict__ W1,
    const float* __restrict__ W2,
    unsigned short* __restrict__ g_bf16, unsigned short* __restrict__ WaF,
    unsigned short* __restrict__ WbF, unsigned short* __restrict__ WcF,
    unsigned short* __restrict__ W2TF)
{
  int bid = blockIdx.x, tid = threadIdx.x;
  if (bid < 256) {
    int t = bid * 256 + tid;
    f32x4 v = ((const f32x4*)g)[t];
    u32x2 o; o[0] = pk_bf16(v[0], v[1]); o[1] = pk_bf16(v[2], v[3]);
    ((u32x2*)g_bf16)[t] = o;
  } else if (bid < 416) {
    int T = (bid - 256) * 256 + tid;         // 0..40959
    int row = T >> 2, q = T & 3;             // row 0..10239 = 16kt*10ht*64lane
    int kt = row / 640; int rem = row - kt * 640;
    int l = rem & 63; int chh = rem >> 6;
    int e = kt * 32 + (l >> 4) * 8 + 2 * q;
    int h = chh * 16 + (l & 15);
    float va0 = 0.f, va1 = 0.f, vb0 = 0.f, vb1 = 0.f, vc0 = 0.f, vc1 = 0.f;
    if (h < NH) {
      va0 = W1[(size_t)e * NH + h];           va1 = W1[(size_t)(e + 1) * NH + h];
      vb0 = W1[(size_t)(512 + e) * NH + h];   vb1 = W1[(size_t)(513 + e) * NH + h];
      vc0 = W1[(size_t)(1024 + e) * NH + h];  vc1 = W1[(size_t)(1025 + e) * NH + h];
    }
    ((unsigned*)WaF)[row * 4 + q] = pk_bf16(va0, va1);
    ((unsigned*)WbF)[row * 4 + q] = pk_bf16(vb0, vb1);
    ((unsigned*)WcF)[row * 4 + q] = pk_bf16(vc0, vc1);
  } else {
    int T = (bid - 416) * 256 + tid;         // 0..12799
    int row = T >> 2, q = T & 3;             // row 0..3199 = 5s*10ht*64lane
    int s = row / 640; int rem = row - s * 640;
    int l = rem & 63; int chh = rem >> 6;
    int k = s * 32 + (l >> 4) * 8 + 2 * q;
    int hp = chh * 16 + (l & 15);
    float v0 = (k < NH && hp < NH)     ? W2[(size_t)k * NH + hp]       : 0.f;
    float v1 = (k + 1 < NH && hp < NH) ? W2[(size_t)(k + 1) * NH + hp] : 0.f;
    ((unsigned*)W2TF)[row * 4 + q] = pk_bf16(v0, v1);
  }
}

// ---------- kernel 1: h1 for one (b,i,hg): 512 thr, 8 jg-waves ----------
// h1g layout: 16B units [bi][hu][j], hu = h/8 in [0,20), j in [0,256)
__global__ __launch_bounds__(512) void pair_h1(
    const float* __restrict__ b1,
    const unsigned short* __restrict__ g_bf16,
    const unsigned short* __restrict__ WaF,
    const unsigned short* __restrict__ WbF, const unsigned short* __restrict__ WcF,
    unsigned* __restrict__ h1g)
{
  __shared__ unsigned tbuf[NN * TS];        // 45056 B: stage dbuf (2x20KB) / transpose
  __shared__ unsigned gi_lds[NE / 2];       // 1 KB
  __shared__ alignas(16) float bias1[80];   // b1 + hi for this hg half

  const int tid = threadIdx.x;
  const int bi = blockIdx.x >> 1;           // b*256+i
  const int hg = blockIdx.x & 1;
  const int b = bi >> 8;
  const int lane = tid & 63, wave = tid >> 6;   // 8 waves = jg
  const int c16 = lane & 15, quad = lane >> 4;
  const int jg = wave;

  // ---- phase 0 ----
  if (tid < 64) {
    const u32x4* grow = (const u32x4*)(g_bf16 + (size_t)bi * NE);
    ((u32x4*)gi_lds)[tid] = grow[tid];
  }
  if (tid >= 64 && tid < 64 + 80) {
    int hl = tid - 64;
    int h = hg * 80 + hl;
    bias1[hl] = (h < NH) ? b1[h] : 0.f;
  }
  __syncthreads();   // barrier A

  // ---- builder: 4-kt half-tile (5 ht), 1280 rows, into given buffer ----
  auto build_tile = [&](int t, unsigned* dst) {
#pragma unroll
    for (int r = 0; r < 3; ++r) {
      int v = tid + r * 512;                // 0..1279 (r=2: tid<256)
      if (r < 2 || tid < 256) {
        int ktl = v / 320; int rem = v - ktl * 320;
        int ch = rem >> 6, l = rem & 63;
        int ktg = t * 4 + ktl;
        int gw = (ktg * NHT + hg * 5 + ch) * 64 + l;
        u32x4 wb = ((const u32x4*)WbF)[gw];
        u32x4 wc = ((const u32x4*)WcF)[gw];
        u32x4 gi = ((const u32x4*)gi_lds)[ktg * 4 + (l >> 4)];
        u32x4 o;
#pragma unroll
        for (int q = 0; q < 4; ++q) {
          float lo = bf_lo(gi[q]) * bf_lo(wc[q]) + bf_lo(wb[q]);
          float hi = bf_hi(gi[q]) * bf_hi(wc[q]) + bf_hi(wb[q]);
          o[q] = pk_bf16(lo, hi);
        }
        ((u32x4*)dst)[v] = o;
      }
    }
  };

  build_tile(0, tbuf);
  // waves 0-4: hi for own ht via mini-MFMA with broadcast-B (g_i per k)
  if (wave < 5) {
    const int HT = hg * 5 + wave;
    f32x4 ah = {};
#pragma unroll
    for (int kt = 0; kt < NKT; ++kt) {
      short8 bbc = __builtin_bit_cast(short8, ((const u32x4*)gi_lds)[kt * 4 + quad]);
      short8 a0 = __builtin_bit_cast(short8,
          ((const u32x4*)WaF)[(kt * NHT + HT) * 64 + lane]);
      ah = __builtin_amdgcn_mfma_f32_16x16x32_bf16(a0, bbc, ah, 0, 0, 0);
    }
    if (c16 == 0) {
#pragma unroll
      for (int r = 0; r < 4; ++r)
        bias1[wave * 16 + quad * 4 + r] += ah[r];
    }
  }
  __syncthreads();   // barrier B: tile 0 ready

  // ---- phase 1: 4 tiles x (4 kt x 5 ht x 2 jt), double-buffered ----
  f32x4 acc1[5][2] = {};
  const u32x4* gB = (const u32x4*)g_bf16;
  const int jbase = jg * 32 + c16;
  const size_t gidx0 = (size_t)(b * NN + jbase) * 64 + quad;

#pragma unroll 1
  for (int t = 0; t < 4; ++t) {
    unsigned* cur = tbuf + (t & 1) * 5120;
    if (t < 3) build_tile(t + 1, tbuf + ((t + 1) & 1) * 5120);
#pragma unroll
    for (int ktl = 0; ktl < 4; ++ktl) {
      int ktg = t * 4 + ktl;
      short8 bf0 = __builtin_bit_cast(short8, gB[gidx0 + (size_t)ktg * 4]);
      short8 bf1 = __builtin_bit_cast(short8, gB[gidx0 + 16 * 64 + (size_t)ktg * 4]);
      const u32x4* As = (const u32x4*)cur + ktl * 320;
#pragma unroll
      for (int ht = 0; ht < 5; ++ht) {
        short8 af = __builtin_bit_cast(short8, As[ht * 64 + lane]);
        acc1[ht][0] = __builtin_amdgcn_mfma_f32_16x16x32_bf16(af, bf0, acc1[ht][0], 0, 0, 0);
        acc1[ht][1] = __builtin_amdgcn_mfma_f32_16x16x32_bf16(af, bf1, acc1[ht][1], 0, 0, 0);
      }
    }
    __syncthreads(); // tile t reads done; tile t+1 build complete
  }

  // ---- epilogue: relu(acc1+bias1) -> bf16 -> LDS transpose [j][h-half] ----
#pragma unroll
  for (int ht = 0; ht < 5; ++ht) {
    f32x4 bv = *(const f32x4*)(bias1 + ht * 16 + quad * 4);
#pragma unroll
    for (int jt = 0; jt < 2; ++jt) {
      f32x4 v = acc1[ht][jt];
      float r0 = fmaxf(v[0] + bv[0], 0.f);
      float r1 = fmaxf(v[1] + bv[1], 0.f);
      float r2 = fmaxf(v[2] + bv[2], 0.f);
      float r3 = fmaxf(v[3] + bv[3], 0.f);
      int j = jg * 32 + jt * 16 + c16;
      int u = j * TS + ht * 8 + quad * 2;
      tbuf[u]     = pk_bf16(r0, r1);
      tbuf[u + 1] = pk_bf16(r2, r3);
    }
  }
  __syncthreads();

  // ---- coalesced store to h1g in B-frag unit layout ----
#pragma unroll
  for (int r = 0; r < 5; ++r) {
    int u = tid + r * 512;                  // 0..2559
    int j = u & 255, hul = u >> 8;          // hul 0..9
    u32x4 d = *(const u32x4*)(tbuf + j * TS + hul * 4);
    ((u32x4*)h1g)[((size_t)bi * 20 + hg * 10 + hul) * 256 + j] = d;
  }
}

// ---------- kernel 2: out for one (b,i,j-half): 512 thr, 2 hgp x 4 jg ----------
__global__ __launch_bounds__(512) void pair_out(
    const float* __restrict__ mention, const float* __restrict__ b2,
    const float* __restrict__ W3, const float* __restrict__ b3,
    const unsigned short* __restrict__ W2TF, const unsigned* __restrict__ h1g,
    float* __restrict__ out)
{
  __shared__ alignas(16) float bias2[HP];
  __shared__ alignas(16) float w3s[HP];
  __shared__ float ps[128];

  const int tid = threadIdx.x;
  const int bi = blockIdx.x >> 1;
  const int jh = blockIdx.x & 1;
  const int b = bi >> 8, i = bi & 255;
  const int lane = tid & 63, wave = tid >> 6;
  const int c16 = lane & 15, quad = lane >> 4;
  const int hgp = wave & 1, jg = wave >> 1;   // 2 x 4

  if (tid < HP) {
    bias2[tid] = (tid < NH) ? b2[tid] : 0.f;
    w3s[tid]   = (tid < NH) ? W3[tid] : 0.f;
  }
  __syncthreads();

  // ---- K=160 GEMM: D2 = W2^T * h1 ; A from L2 ping-pong, B from h1g ----
  f32x4 acc2[5][2] = {};
  u32x4 wf[2][5];
#pragma unroll
  for (int ht = 0; ht < 5; ++ht)
    wf[0][ht] = ((const u32x4*)W2TF)[(hgp * 5 + ht) * 64 + lane];

#pragma unroll
  for (int s = 0; s < NS; ++s) {
    if (s + 1 < NS) {
#pragma unroll
      for (int ht = 0; ht < 5; ++ht)
        wf[(s + 1) & 1][ht] =
            ((const u32x4*)W2TF)[((s + 1) * NHT + hgp * 5 + ht) * 64 + lane];
    }
    short8 b2f[2];
#pragma unroll
    for (int jt = 0; jt < 2; ++jt) {
      int j = jh * 128 + jg * 32 + jt * 16 + c16;
      int hu = s * 4 + quad;
      b2f[jt] = __builtin_bit_cast(short8,
          ((const u32x4*)h1g)[((size_t)bi * 20 + hu) * 256 + j]);
    }
#pragma unroll
    for (int ht = 0; ht < 5; ++ht) {
      short8 af = __builtin_bit_cast(short8, wf[s & 1][ht]);
      acc2[ht][0] = __builtin_amdgcn_mfma_f32_16x16x32_bf16(af, b2f[0], acc2[ht][0], 0, 0, 0);
      acc2[ht][1] = __builtin_amdgcn_mfma_f32_16x16x32_bf16(af, b2f[1], acc2[ht][1], 0, 0, 0);
    }
  }

  // ---- epilogue + GEMM3: partial over own h' range ----
  float part0 = 0.f, part1 = 0.f;
#pragma unroll
  for (int ht = 0; ht < 5; ++ht) {
    int HT = hgp * 5 + ht;
    f32x4 bv = *(const f32x4*)(bias2 + HT * 16 + quad * 4);
    f32x4 wv = *(const f32x4*)(w3s + HT * 16 + quad * 4);
    f32x4 v0 = acc2[ht][0], v1 = acc2[ht][1];
#pragma unroll
    for (int r = 0; r < 4; ++r) {
      part0 += fmaxf(v0[r] + bv[r], 0.f) * wv[r];
      part1 += fmaxf(v1[r] + bv[r], 0.f) * wv[r];
    }
  }
  part0 += __shfl_xor(part0, 16); part0 += __shfl_xor(part0, 32);
  part1 += __shfl_xor(part1, 16); part1 += __shfl_xor(part1, 32);

  if (hgp == 0) {
    if (quad == 0) ps[jg * 32 + c16] = part0;
    if (quad == 1) ps[jg * 32 + 16 + c16] = part1;
  }
  __syncthreads();

  if (hgp == 1 && quad < 2) {
    int jl = jg * 32 + quad * 16 + c16;
    int j = jh * 128 + jl;
    float sc = (quad == 0) ? part0 : part1;
    float mi = mention[b * NN + i];
    float mj = mention[b * NN + j];
    out[((size_t)(b * NN + i)) * NN + j] =
        (mi + mj + ps[jl] + sc + b3[0]) * (1.f / 3.f);
  }
}

// ---------- launch ----------
extern "C" void kernel_launch(void* const* d_in, const int* in_sizes, int n_in,
                              void* d_out, int out_size, void* d_ws, size_t ws_size,
                              hipStream_t stream) {
  const float* g  = (const float*)d_in[0];
  const float* m  = (const float*)d_in[1];
  const float* W1 = (const float*)d_in[2];
  const float* b1 = (const float*)d_in[3];
  const float* W2 = (const float*)d_in[4];
  const float* b2 = (const float*)d_in[5];
  const float* W3 = (const float*)d_in[6];
  const float* b3 = (const float*)d_in[7];
  float* out = (float*)d_out;

  char* ws = (char*)d_ws;
  unsigned short* g_bf16 = (unsigned short*)(ws);              // 524288 B
  unsigned short* WaF    = (unsigned short*)(ws + 524288);     // 163840 B
  unsigned short* WbF    = (unsigned short*)(ws + 688128);     // 163840 B
  unsigned short* WcF    = (unsigned short*)(ws + 851968);     // 163840 B
  unsigned short* W2TF   = (unsigned short*)(ws + 1015808);    //  51200 B
  unsigned*       h1g    = (unsigned*)(ws + 1067008);          // 41.94 MB (total ~43 MB)

  prep_pack<<<466, 256, 0, stream>>>(g, W1, W2, g_bf16, WaF, WbF, WcF, W2TF);
  pair_h1<<<1024, 512, 0, stream>>>(b1, g_bf16, WaF, WbF, WcF, h1g);
  pair_out<<<1024, 512, 0, stream>>>(m, b2, W3, b3, W2TF, h1g, out);
}